// Round 5
// baseline (413.048 us; speedup 1.0000x reference)
//
#include <hip/hip_runtime.h>
#include <hip/hip_bf16.h>

typedef unsigned int u32;
typedef unsigned short u16;
typedef __attribute__((ext_vector_type(8))) short short8;
typedef __attribute__((ext_vector_type(4))) float f32x4;

#define EPSV 1e-5f
#define MAXN (1.0f - 1e-5f)
#define THETA 0.17f
#define CAP 512

__device__ __forceinline__ u16 f2bf(float f) {
    union { float f; u32 u; } v; v.f = f;
    u32 u = v.u;
    u32 r = (u + 0x7fffu + ((u >> 16) & 1u)) >> 16;
    return (u16)r;
}
__device__ __forceinline__ float bf2f(u16 h) {
    union { u32 u; float f; } v; v.u = ((u32)h) << 16;
    return v.f;
}

typedef __attribute__((address_space(1))) const unsigned char gbuf_t;
typedef __attribute__((address_space(3))) unsigned char lbuf_t;
__device__ __forceinline__ void gl2lds16(const void* g, void* l) {
    __builtin_amdgcn_global_load_lds((gbuf_t*)g, (lbuf_t*)l, 16, 0, 0);
}

// ---------------- fused pre: memory project + hidden->bf16 + weight transposes ----------------
__global__ __launch_bounds__(256) void k_pre(const float* __restrict__ mem,
                                             u16* __restrict__ mbf,
                                             float* __restrict__ y2m,
                                             u32* __restrict__ cnt,
                                             const float* __restrict__ hidden, u16* __restrict__ hb,
                                             const float* __restrict__ w1, u16* __restrict__ w1t,
                                             const float* __restrict__ w2, u16* __restrict__ w2t,
                                             const float* __restrict__ wp, u16* __restrict__ wpt) {
    const int b = blockIdx.x, t = threadIdx.x;
    if (b < 16384) {                      // memory bank: project + bf16 + y2
        int zi = b * 256 + t;
        if (zi < 2048) cnt[zi] = 0;
        const int row = b * 4 + (t >> 6);
        const int lane = t & 63;
        const float4* p = (const float4*)(mem + (size_t)row * 256);
        float4 v = p[lane];
        float ss = v.x * v.x + v.y * v.y + v.z * v.z + v.w * v.w;
#pragma unroll
        for (int off = 32; off; off >>= 1) ss += __shfl_xor(ss, off);
        float norm = sqrtf(ss);
        float scale = (norm > MAXN) ? MAXN / fmaxf(norm, EPSV) : 1.0f;
        ushort4 u;
        u.x = f2bf(v.x * scale); u.y = f2bf(v.y * scale);
        u.z = f2bf(v.z * scale); u.w = f2bf(v.w * scale);
        *(ushort4*)&mbf[(size_t)row * 256 + lane * 4] = u;
        if (lane == 0) y2m[row] = ss * scale * scale;
    } else if (b < 18432) {               // hidden f32 -> bf16
        int i = (b - 16384) * 256 + t;
        float4 v = ((const float4*)hidden)[i];
        ushort4 u; u.x = f2bf(v.x); u.y = f2bf(v.y); u.z = f2bf(v.z); u.w = f2bf(v.w);
        ((ushort4*)hb)[i] = u;
    } else if (b < 19456) {               // w1t[n*1024+k] = w1[k*256+n]
        int idx = (b - 18432) * 256 + t;
        int nn = idx >> 10, kk = idx & 1023;
        w1t[idx] = f2bf(w1[(size_t)kk * 256 + nn]);
    } else if (b < 19712) {               // w2t[n*256+k] = w2[k*256+n]
        int idx = (b - 19456) * 256 + t;
        int nn = idx >> 8, kk = idx & 255;
        w2t[idx] = f2bf(w2[(size_t)kk * 256 + nn]);
    } else {                              // wpt[n*256+k] = wp[k*1024+n]
        int idx = (b - 19712) * 256 + t;
        int nn = idx >> 8, kk = idx & 255;
        wpt[idx] = f2bf(wp[(size_t)kk * 1024 + nn]);
    }
}

// ---------------- GEMM1 (2048x1024x256) + bias + LayerNorm + GELU -> qg bf16 ----------------
__global__ __launch_bounds__(256) void k_g1(const u16* __restrict__ hb,
                                            const u16* __restrict__ w1t,
                                            const float* __restrict__ b1,
                                            const float* __restrict__ lng,
                                            const float* __restrict__ lnb,
                                            u16* __restrict__ qg) {
    __shared__ float sm[16 * 260];
    const int t = threadIdx.x;
    const int w = t >> 6, lane = t & 63;
    const int l16 = lane & 15, kq = (lane >> 4) * 8, rbase = (lane >> 4) * 4;
    const int q0 = blockIdx.x * 16;
    f32x4 zero = {0.f, 0.f, 0.f, 0.f};
    f32x4 acc[4] = {zero, zero, zero, zero};
    const u16* ap = hb + (size_t)(q0 + l16) * 1024 + kq;
    for (int k0 = 0; k0 < 1024; k0 += 32) {
        short8 av = *(const short8*)(ap + k0);
#pragma unroll
        for (int ct = 0; ct < 4; ++ct) {
            int n = w * 64 + ct * 16 + l16;
            short8 bv = *(const short8*)&w1t[(size_t)n * 1024 + k0 + kq];
            acc[ct] = __builtin_amdgcn_mfma_f32_16x16x32_bf16(av, bv, acc[ct], 0, 0, 0);
        }
    }
#pragma unroll
    for (int ct = 0; ct < 4; ++ct) {
        int n = w * 64 + ct * 16 + l16;
        float bias = b1[n];
#pragma unroll
        for (int r = 0; r < 4; ++r)
            sm[(rbase + r) * 260 + n] = acc[ct][r] + bias;
    }
    __syncthreads();
    const int row = t >> 4, sub = t & 15;
    float s1 = 0.f, s2 = 0.f;
#pragma unroll
    for (int i = 0; i < 16; ++i) {
        float v = sm[row * 260 + sub + 16 * i];
        s1 += v; s2 += v * v;
    }
#pragma unroll
    for (int off = 8; off; off >>= 1) {
        s1 += __shfl_xor(s1, off, 16);
        s2 += __shfl_xor(s2, off, 16);
    }
    float mu = s1 * (1.0f / 256.0f);
    float var = s2 * (1.0f / 256.0f) - mu * mu;
    float rstd = rsqrtf(var + EPSV);
#pragma unroll
    for (int i = 0; i < 16; ++i) {
        int cc = sub + 16 * i;
        float v = sm[row * 260 + cc];
        float xn = (v - mu) * rstd * lng[cc] + lnb[cc];
        float ge = 0.5f * xn * (1.0f + erff(xn * 0.7071067811865475f));
        qg[(size_t)(q0 + row) * 256 + cc] = f2bf(ge);
    }
}

// ---------------- GEMM2 (2048x256x256) + bias + Poincare project -> qb bf16, x2 ----------------
__global__ __launch_bounds__(256) void k_g2(const u16* __restrict__ qg,
                                            const u16* __restrict__ w2t,
                                            const float* __restrict__ b2,
                                            u16* __restrict__ qbb,
                                            float* __restrict__ x2q) {
    __shared__ float sm[16 * 260];
    const int t = threadIdx.x;
    const int w = t >> 6, lane = t & 63;
    const int l16 = lane & 15, kq = (lane >> 4) * 8, rbase = (lane >> 4) * 4;
    const int q0 = blockIdx.x * 16;
    f32x4 zero = {0.f, 0.f, 0.f, 0.f};
    f32x4 acc[4] = {zero, zero, zero, zero};
    const u16* ap = qg + (size_t)(q0 + l16) * 256 + kq;
    for (int k0 = 0; k0 < 256; k0 += 32) {
        short8 av = *(const short8*)(ap + k0);
#pragma unroll
        for (int ct = 0; ct < 4; ++ct) {
            int n = w * 64 + ct * 16 + l16;
            short8 bv = *(const short8*)&w2t[(size_t)n * 256 + k0 + kq];
            acc[ct] = __builtin_amdgcn_mfma_f32_16x16x32_bf16(av, bv, acc[ct], 0, 0, 0);
        }
    }
#pragma unroll
    for (int ct = 0; ct < 4; ++ct) {
        int n = w * 64 + ct * 16 + l16;
        float bias = b2[n];
#pragma unroll
        for (int r = 0; r < 4; ++r)
            sm[(rbase + r) * 260 + n] = acc[ct][r] + bias;
    }
    __syncthreads();
    const int row = t >> 4, sub = t & 15;
    float s2 = 0.f;
#pragma unroll
    for (int i = 0; i < 16; ++i) {
        float v = sm[row * 260 + sub + 16 * i];
        s2 += v * v;
    }
#pragma unroll
    for (int off = 8; off; off >>= 1) s2 += __shfl_xor(s2, off, 16);
    float norm = sqrtf(s2);
    float scale = (norm > MAXN) ? MAXN / fmaxf(norm, EPSV) : 1.0f;
    if (sub == 0) x2q[q0 + row] = s2 * scale * scale;
#pragma unroll
    for (int i = 0; i < 16; ++i) {
        int cc = sub + 16 * i;
        qbb[(size_t)(q0 + row) * 256 + cc] = f2bf(sm[row * 260 + cc] * scale);
    }
}

// ---------------- main: single-barrier MFMA GEMM + threshold candidate collection ----
// 128x128 tile, full K=256 in one pass. A (q-tile) -> LDS once via DMA (64 KB,
// XOR chunk-swizzle slot = chunk ^ (r&7)); B (m-rows) -> registers, wave w owns
// the DISJOINT 32 m-rows [m0+w*32, +32) for all K (bv[8][2], no duplicate fetch).
// All 32 VMEM issues in flight before ONE vmcnt(0)+barrier; K-loop has no barriers.
// XCD-clustered dispatch as R4 (B-tile sharers consecutive on same XCD).
__global__ __launch_bounds__(256, 2) void k_dist(const u16* __restrict__ qb,
                                                 const u16* __restrict__ mbf,
                                                 u32* __restrict__ cnt,
                                                 uint2* __restrict__ cand) {
    __shared__ u16 As[128 * 256];         // 64 KB: As[r*256 + slot*8], slot = chunk ^ (r&7)
    const int b = blockIdx.x;
    const int qt = (b >> 3) & 15;
    const int mt = ((b >> 7) << 3) | (b & 7);
    const int q0 = qt * 128, m0 = mt * 128;
    const int t = threadIdx.x;
    const int w = t >> 6, lane = t & 63;
    const int l16 = lane & 15, Q = lane >> 4, rbase = Q * 4;

    // ---- B -> registers: row = m0 + w*32 + ct*16 + l16, chunk = ks*4 + Q (16 B)
    short8 bv[8][2];
    {
        const u16* bb = mbf + (size_t)(m0 + w * 32 + l16) * 256 + Q * 8;
#pragma unroll
        for (int ks = 0; ks < 8; ++ks)
#pragma unroll
            for (int ct = 0; ct < 2; ++ct)
                bv[ks][ct] = *(const short8*)(bb + ct * 16 * 256 + ks * 32);
    }
    // ---- A -> LDS via DMA: issue i covers rows [i*2, i*2+2); lane slot = lane&31
    //      holds global chunk (lane&31) ^ (r&7)
#pragma unroll
    for (int j = 0; j < 16; ++j) {
        int i = w * 16 + j;
        int r = i * 2 + (lane >> 5);
        int c = (lane & 31) ^ (r & 7);
        gl2lds16(qb + (size_t)(q0 + r) * 256 + c * 8, As + i * 512);
    }
    __syncthreads();                      // ONE drain: A in LDS, bv landed

    f32x4 zero = {0.f, 0.f, 0.f, 0.f};
    f32x4 acc[8][2];
#pragma unroll
    for (int i = 0; i < 8; ++i) { acc[i][0] = zero; acc[i][1] = zero; }
    const int rx = l16 & 7;
    int Rb[8];
#pragma unroll
    for (int i = 0; i < 8; ++i) Rb[i] = (i * 16 + l16) * 256;

#pragma unroll
    for (int ks = 0; ks < 8; ++ks) {
        const int slot = ((ks * 4 + Q) ^ rx) * 8;
        short8 av[8];
#pragma unroll
        for (int i = 0; i < 8; ++i) av[i] = *(const short8*)(As + Rb[i] + slot);
#pragma unroll
        for (int rt = 0; rt < 8; ++rt)
#pragma unroll
            for (int ct = 0; ct < 2; ++ct)
                acc[rt][ct] = __builtin_amdgcn_mfma_f32_16x16x32_bf16(av[rt], bv[ks][ct], acc[rt][ct], 0, 0, 0);
    }

    // epilogue: threshold + candidate append
#pragma unroll
    for (int rt = 0; rt < 8; ++rt)
#pragma unroll
        for (int ct = 0; ct < 2; ++ct)
#pragma unroll
            for (int r = 0; r < 4; ++r) {
                float d = acc[rt][ct][r];
                if (d > THETA) {
                    int q = q0 + rt * 16 + rbase + r;
                    int m = m0 + w * 32 + ct * 16 + l16;
                    u32 pos = atomicAdd(&cnt[q], 1u);
                    if (pos < CAP) cand[(size_t)q * CAP + pos] = make_uint2((u32)m, __float_as_uint(d));
                }
            }
}

// ---------------- merge: exact top-16, softmax(-dist), weighted gather -> rb bf16 ----------------
__global__ __launch_bounds__(64, 4) void k_merge(const u32* __restrict__ cnt,
                                                 const uint2* __restrict__ cand,
                                                 const float* __restrict__ x2q,
                                                 const float* __restrict__ y2m,
                                                 const u16* __restrict__ mbf,
                                                 u16* __restrict__ rb) {
    const int q = blockIdx.x;
    const int lane = threadIdx.x;
    int n = (int)cnt[q]; if (n > CAP) n = CAP;
    const float x2 = x2q[q];
    const float dx = 1.0f - x2;
    float rv[8]; u32 mi[8];
#pragma unroll
    for (int j = 0; j < 8; ++j) {
        int idx = lane + 64 * j;
        rv[j] = 3.0e38f; mi[j] = 0;
        if (idx < n) {
            uint2 c = cand[(size_t)q * CAP + idx];
            float dot = __uint_as_float(c.y);
            float y2 = y2m[c.x];
            float sq = fmaxf(x2 + y2 - 2.0f * dot, 0.0f);
            float den = fmaxf(dx * (1.0f - y2), EPSV);
            rv[j] = sq / den;
            mi[j] = c.x;
        }
    }
    __shared__ float sdist[16];
    __shared__ u32 smi[16];
    __shared__ float swt[16];
    for (int k = 0; k < 16; ++k) {
        float lm = rv[0]; int ls = 0;
#pragma unroll
        for (int j = 1; j < 8; ++j) if (rv[j] < lm) { lm = rv[j]; ls = j; }
        unsigned long long key = (((unsigned long long)__float_as_uint(lm)) << 32) | (u32)(lane * 8 + ls);
#pragma unroll
        for (int off = 32; off; off >>= 1) {
            unsigned long long o = __shfl_xor(key, off);
            key = (o < key) ? o : key;
        }
        u32 sid = (u32)(key & 0xffffffffu);
        int wl = (int)(sid >> 3), wslot = (int)(sid & 7);
        if (lane == wl) {
            sdist[k] = rv[wslot];
            smi[k] = mi[wslot];
            rv[wslot] = 3.0e38f;
        }
    }
    __syncthreads();
    float rr = sdist[lane & 15];
    float arg = fmaxf(fmaf(2.0f, rr, 1.0f), 1.0f + EPSV);
    float dneg = -acoshf(arg);
    float mx = dneg;
#pragma unroll
    for (int off = 8; off; off >>= 1) mx = fmaxf(mx, __shfl_xor(mx, off, 16));
    float e = expf(dneg - mx);
    float ssum = e;
#pragma unroll
    for (int off = 8; off; off >>= 1) ssum += __shfl_xor(ssum, off, 16);
    if (lane < 16) swt[lane] = e / ssum;
    __syncthreads();
    float acc[4] = {0.f, 0.f, 0.f, 0.f};
    for (int k = 0; k < 16; ++k) {
        float wk = swt[k];
        const u16* mr = mbf + (size_t)smi[k] * 256;
#pragma unroll
        for (int j = 0; j < 4; ++j) acc[j] += wk * bf2f(mr[lane + 64 * j]);
    }
#pragma unroll
    for (int j = 0; j < 4; ++j) rb[(size_t)q * 256 + lane + 64 * j] = f2bf(acc[j]);
}

// ---------------- output: out = hidden + 0.1*(rb @ wp + bp) ----------------
__global__ __launch_bounds__(256) void k_out(const u16* __restrict__ rb,
                                             const u16* __restrict__ wpt,
                                             const float* __restrict__ bp,
                                             const float* __restrict__ hidden,
                                             float* __restrict__ out) {
    const int b = blockIdx.x;
    const int mt = b & 31, nt = b >> 5;
    const int t = threadIdx.x;
    const int w = t >> 6, lane = t & 63;
    const int l16 = lane & 15, kq = (lane >> 4) * 8, rbase = (lane >> 4) * 4;
    const int n = nt * 64 + w * 16 + l16;
    f32x4 zero = {0.f, 0.f, 0.f, 0.f};
    f32x4 acc[4] = {zero, zero, zero, zero};
    for (int k0 = 0; k0 < 256; k0 += 32) {
        short8 bv = *(const short8*)&wpt[(size_t)n * 256 + k0 + kq];
#pragma unroll
        for (int rt = 0; rt < 4; ++rt) {
            short8 av = *(const short8*)&rb[(size_t)(mt * 64 + rt * 16 + l16) * 256 + k0 + kq];
            acc[rt] = __builtin_amdgcn_mfma_f32_16x16x32_bf16(av, bv, acc[rt], 0, 0, 0);
        }
    }
    float bpn = bp[n];
#pragma unroll
    for (int rt = 0; rt < 4; ++rt)
#pragma unroll
        for (int r = 0; r < 4; ++r) {
            int m = mt * 64 + rt * 16 + rbase + r;
            out[(size_t)m * 1024 + n] = hidden[(size_t)m * 1024 + n] + 0.1f * (acc[rt][r] + bpn);
        }
}

extern "C" void kernel_launch(void* const* d_in, const int* in_sizes, int n_in,
                              void* d_out, int out_size, void* d_ws, size_t ws_size,
                              hipStream_t stream) {
    const float* hidden = (const float*)d_in[0];
    const float* memory = (const float*)d_in[1];
    const float* w1 = (const float*)d_in[2];
    const float* b1 = (const float*)d_in[3];
    const float* ln_g = (const float*)d_in[4];
    const float* ln_b = (const float*)d_in[5];
    const float* w2 = (const float*)d_in[6];
    const float* b2 = (const float*)d_in[7];
    const float* wp = (const float*)d_in[8];
    const float* bp = (const float*)d_in[9];
    float* out = (float*)d_out;
    char* ws = (char*)d_ws;

    u16* mbf  = (u16*)(ws);                       // 33554432
    float* y2m = (float*)(ws + 33554432);         // 262144
    u16* hb   = (u16*)(ws + 33816576);            // 4194304
    u16* w1t  = (u16*)(ws + 38010880);            // 524288
    u16* w2t  = (u16*)(ws + 38535168);            // 131072
    u16* wpt  = (u16*)(ws + 38666240);            // 524288
    u16* qg   = (u16*)(ws + 39190528);            // 1048576
    u16* qbb  = (u16*)(ws + 40239104);            // 1048576
    float* x2q = (float*)(ws + 41287680);         // 8192
    u32* cnt  = (u32*)(ws + 41295872);            // 8192
    uint2* cand = (uint2*)(ws + 41304064);        // 8388608
    u16* rb   = (u16*)(ws + 49692672);            // 1048576

    hipLaunchKernelGGL(k_pre, dim3(19968), dim3(256), 0, stream,
                       memory, mbf, y2m, cnt, hidden, hb, w1, w1t, w2, w2t, wp, wpt);
    hipLaunchKernelGGL(k_g1, dim3(128), dim3(256), 0, stream, hb, w1t, b1, ln_g, ln_b, qg);
    hipLaunchKernelGGL(k_g2, dim3(128), dim3(256), 0, stream, qg, w2t, b2, qbb, x2q);
    hipLaunchKernelGGL(k_dist, dim3(8192), dim3(256), 0, stream, qbb, mbf, cnt, cand);
    hipLaunchKernelGGL(k_merge, dim3(2048), dim3(64), 0, stream, cnt, cand, x2q, y2m, mbf, rb);
    hipLaunchKernelGGL(k_out, dim3(512), dim3(256), 0, stream, rb, wpt, bp, hidden, out);
}

// Round 6
// 322.257 us; speedup vs baseline: 1.2817x; 1.2817x over previous
//
#include <hip/hip_runtime.h>
#include <hip/hip_bf16.h>

typedef unsigned int u32;
typedef unsigned short u16;
typedef __attribute__((ext_vector_type(8))) short short8;
typedef __attribute__((ext_vector_type(4))) float f32x4;

#define EPSV 1e-5f
#define MAXN (1.0f - 1e-5f)
#define THETA 0.17f
#define CAP 512

__device__ __forceinline__ u16 f2bf(float f) {
    union { float f; u32 u; } v; v.f = f;
    u32 u = v.u;
    u32 r = (u + 0x7fffu + ((u >> 16) & 1u)) >> 16;
    return (u16)r;
}
__device__ __forceinline__ float bf2f(u16 h) {
    union { u32 u; float f; } v; v.u = ((u32)h) << 16;
    return v.f;
}

typedef __attribute__((address_space(1))) const unsigned char gbuf_t;
typedef __attribute__((address_space(3))) unsigned char lbuf_t;
__device__ __forceinline__ void gl2lds16(const void* g, void* l) {
    __builtin_amdgcn_global_load_lds((gbuf_t*)g, (lbuf_t*)l, 16, 0, 0);
}

// ---------------- fused pre: memory project + hidden->bf16 + weight transposes ----------------
__global__ __launch_bounds__(256) void k_pre(const float* __restrict__ mem,
                                             u16* __restrict__ mbf,
                                             float* __restrict__ y2m,
                                             u32* __restrict__ cnt,
                                             const float* __restrict__ hidden, u16* __restrict__ hb,
                                             const float* __restrict__ w1, u16* __restrict__ w1t,
                                             const float* __restrict__ w2, u16* __restrict__ w2t,
                                             const float* __restrict__ wp, u16* __restrict__ wpt) {
    const int b = blockIdx.x, t = threadIdx.x;
    if (b < 16384) {                      // memory bank: project + bf16 + y2
        int zi = b * 256 + t;
        if (zi < 2048) cnt[zi] = 0;
        const int row = b * 4 + (t >> 6);
        const int lane = t & 63;
        const float4* p = (const float4*)(mem + (size_t)row * 256);
        float4 v = p[lane];
        float ss = v.x * v.x + v.y * v.y + v.z * v.z + v.w * v.w;
#pragma unroll
        for (int off = 32; off; off >>= 1) ss += __shfl_xor(ss, off);
        float norm = sqrtf(ss);
        float scale = (norm > MAXN) ? MAXN / fmaxf(norm, EPSV) : 1.0f;
        ushort4 u;
        u.x = f2bf(v.x * scale); u.y = f2bf(v.y * scale);
        u.z = f2bf(v.z * scale); u.w = f2bf(v.w * scale);
        *(ushort4*)&mbf[(size_t)row * 256 + lane * 4] = u;
        if (lane == 0) y2m[row] = ss * scale * scale;
    } else if (b < 18432) {               // hidden f32 -> bf16
        int i = (b - 16384) * 256 + t;
        float4 v = ((const float4*)hidden)[i];
        ushort4 u; u.x = f2bf(v.x); u.y = f2bf(v.y); u.z = f2bf(v.z); u.w = f2bf(v.w);
        ((ushort4*)hb)[i] = u;
    } else if (b < 19456) {               // w1t[n*1024+k] = w1[k*256+n]
        int idx = (b - 18432) * 256 + t;
        int nn = idx >> 10, kk = idx & 1023;
        w1t[idx] = f2bf(w1[(size_t)kk * 256 + nn]);
    } else if (b < 19712) {               // w2t[n*256+k] = w2[k*256+n]
        int idx = (b - 19456) * 256 + t;
        int nn = idx >> 8, kk = idx & 255;
        w2t[idx] = f2bf(w2[(size_t)kk * 256 + nn]);
    } else {                              // wpt[n*256+k] = wp[k*1024+n]
        int idx = (b - 19712) * 256 + t;
        int nn = idx >> 8, kk = idx & 255;
        wpt[idx] = f2bf(wp[(size_t)kk * 1024 + nn]);
    }
}

// ---------------- GEMM1 (2048x1024x256) + bias + LayerNorm + GELU -> qg bf16 ----------------
__global__ __launch_bounds__(256) void k_g1(const u16* __restrict__ hb,
                                            const u16* __restrict__ w1t,
                                            const float* __restrict__ b1,
                                            const float* __restrict__ lng,
                                            const float* __restrict__ lnb,
                                            u16* __restrict__ qg) {
    __shared__ float sm[16 * 260];
    const int t = threadIdx.x;
    const int w = t >> 6, lane = t & 63;
    const int l16 = lane & 15, kq = (lane >> 4) * 8, rbase = (lane >> 4) * 4;
    const int q0 = blockIdx.x * 16;
    f32x4 zero = {0.f, 0.f, 0.f, 0.f};
    f32x4 acc[4] = {zero, zero, zero, zero};
    const u16* ap = hb + (size_t)(q0 + l16) * 1024 + kq;
    for (int k0 = 0; k0 < 1024; k0 += 32) {
        short8 av = *(const short8*)(ap + k0);
#pragma unroll
        for (int ct = 0; ct < 4; ++ct) {
            int n = w * 64 + ct * 16 + l16;
            short8 bv = *(const short8*)&w1t[(size_t)n * 1024 + k0 + kq];
            acc[ct] = __builtin_amdgcn_mfma_f32_16x16x32_bf16(av, bv, acc[ct], 0, 0, 0);
        }
    }
#pragma unroll
    for (int ct = 0; ct < 4; ++ct) {
        int n = w * 64 + ct * 16 + l16;
        float bias = b1[n];
#pragma unroll
        for (int r = 0; r < 4; ++r)
            sm[(rbase + r) * 260 + n] = acc[ct][r] + bias;
    }
    __syncthreads();
    const int row = t >> 4, sub = t & 15;
    float s1 = 0.f, s2 = 0.f;
#pragma unroll
    for (int i = 0; i < 16; ++i) {
        float v = sm[row * 260 + sub + 16 * i];
        s1 += v; s2 += v * v;
    }
#pragma unroll
    for (int off = 8; off; off >>= 1) {
        s1 += __shfl_xor(s1, off, 16);
        s2 += __shfl_xor(s2, off, 16);
    }
    float mu = s1 * (1.0f / 256.0f);
    float var = s2 * (1.0f / 256.0f) - mu * mu;
    float rstd = rsqrtf(var + EPSV);
#pragma unroll
    for (int i = 0; i < 16; ++i) {
        int cc = sub + 16 * i;
        float v = sm[row * 260 + cc];
        float xn = (v - mu) * rstd * lng[cc] + lnb[cc];
        float ge = 0.5f * xn * (1.0f + erff(xn * 0.7071067811865475f));
        qg[(size_t)(q0 + row) * 256 + cc] = f2bf(ge);
    }
}

// ---------------- GEMM2 (2048x256x256) + bias + Poincare project -> qb bf16, x2 ----------------
__global__ __launch_bounds__(256) void k_g2(const u16* __restrict__ qg,
                                            const u16* __restrict__ w2t,
                                            const float* __restrict__ b2,
                                            u16* __restrict__ qbb,
                                            float* __restrict__ x2q) {
    __shared__ float sm[16 * 260];
    const int t = threadIdx.x;
    const int w = t >> 6, lane = t & 63;
    const int l16 = lane & 15, kq = (lane >> 4) * 8, rbase = (lane >> 4) * 4;
    const int q0 = blockIdx.x * 16;
    f32x4 zero = {0.f, 0.f, 0.f, 0.f};
    f32x4 acc[4] = {zero, zero, zero, zero};
    const u16* ap = qg + (size_t)(q0 + l16) * 256 + kq;
    for (int k0 = 0; k0 < 256; k0 += 32) {
        short8 av = *(const short8*)(ap + k0);
#pragma unroll
        for (int ct = 0; ct < 4; ++ct) {
            int n = w * 64 + ct * 16 + l16;
            short8 bv = *(const short8*)&w2t[(size_t)n * 256 + k0 + kq];
            acc[ct] = __builtin_amdgcn_mfma_f32_16x16x32_bf16(av, bv, acc[ct], 0, 0, 0);
        }
    }
#pragma unroll
    for (int ct = 0; ct < 4; ++ct) {
        int n = w * 64 + ct * 16 + l16;
        float bias = b2[n];
#pragma unroll
        for (int r = 0; r < 4; ++r)
            sm[(rbase + r) * 260 + n] = acc[ct][r] + bias;
    }
    __syncthreads();
    const int row = t >> 4, sub = t & 15;
    float s2 = 0.f;
#pragma unroll
    for (int i = 0; i < 16; ++i) {
        float v = sm[row * 260 + sub + 16 * i];
        s2 += v * v;
    }
#pragma unroll
    for (int off = 8; off; off >>= 1) s2 += __shfl_xor(s2, off, 16);
    float norm = sqrtf(s2);
    float scale = (norm > MAXN) ? MAXN / fmaxf(norm, EPSV) : 1.0f;
    if (sub == 0) x2q[q0 + row] = s2 * scale * scale;
#pragma unroll
    for (int i = 0; i < 16; ++i) {
        int cc = sub + 16 * i;
        qbb[(size_t)(q0 + row) * 256 + cc] = f2bf(sm[row * 260 + cc] * scale);
    }
}

// ---------------- main: R4 structure scaled to 256q x 128m, 512 threads (8 waves) ----
// BK=64, K=256 (4 stages). Per-wave shape identical to R4 (4x4 MFMA tiles, same
// XOR chunk-swizzle slot = chunk ^ (r&7), measured 0 conflicts). Wave w owns
// quadrant (wq = w&3) * 64 q-rows x (wm = w>>2) * 64 m-rows.
// XCD-clustered dispatch: qt=(b>>3)&7, mt=((b>>6)<<3)|(b&7) -> the 8 blocks
// sharing an m-tile are consecutive on the same XCD.
__global__ __launch_bounds__(512) void k_dist(const u16* __restrict__ qb,
                                              const u16* __restrict__ mbf,
                                              u32* __restrict__ cnt,
                                              uint2* __restrict__ cand) {
    __shared__ u16 smem[24576];           // As[256][64] @0, Bs[128][64] @16384
    u16* As = smem;
    const int b = blockIdx.x;
    const int qt = (b >> 3) & 7;
    const int mt = ((b >> 6) << 3) | (b & 7);
    const int q0 = qt * 256, m0 = mt * 128;
    const int t = threadIdx.x;
    const int w = t >> 6, lane = t & 63;
    const int l16 = lane & 15, Q = lane >> 4, rbase = Q * 4;

    // staging: A issues i = w*4+j (32 total, 8 rows each); B issues i = w*2+j (16 total)
    const u16* pA[4]; u16* lA[4];
    const u16* pB[2]; u16* lB[2];
#pragma unroll
    for (int j = 0; j < 4; ++j) {
        int i = w * 4 + j;
        int r = i * 8 + (lane >> 3);
        int c = (lane & 7) ^ (r & 7);
        pA[j] = qb + (size_t)(q0 + r) * 256 + c * 8;
        lA[j] = As + i * 512;             // wave-uniform base
    }
#pragma unroll
    for (int j = 0; j < 2; ++j) {
        int i = w * 2 + j;
        int r = i * 8 + (lane >> 3);
        int c = (lane & 7) ^ (r & 7);
        pB[j] = mbf + (size_t)(m0 + r) * 256 + c * 8;
        lB[j] = As + 16384 + i * 512;
    }

    // compute-side swizzled LDS offsets (u16 units); h=1 sub-step = offset ^ 32
    const int wq = w & 3, wm = w >> 2;
    int aoff[4], boff[4];
#pragma unroll
    for (int i = 0; i < 4; ++i) {
        int R = wq * 64 + i * 16 + l16;
        aoff[i] = R * 64 + ((Q ^ (R & 7)) * 8);
        int S = wm * 64 + i * 16 + l16;
        boff[i] = 16384 + S * 64 + ((Q ^ (S & 7)) * 8);
    }

    f32x4 zero = {0.f, 0.f, 0.f, 0.f};
    f32x4 acc[4][4];
#pragma unroll
    for (int i = 0; i < 4; ++i)
#pragma unroll
        for (int j = 0; j < 4; ++j) acc[i][j] = zero;

#pragma unroll 1
    for (int kt = 0; kt < 4; ++kt) {
        if (kt) __syncthreads();          // all waves done reading previous tile
#pragma unroll
        for (int j = 0; j < 4; ++j) gl2lds16(pA[j], lA[j]);
#pragma unroll
        for (int j = 0; j < 2; ++j) gl2lds16(pB[j], lB[j]);
#pragma unroll
        for (int j = 0; j < 4; ++j) pA[j] += 64;
#pragma unroll
        for (int j = 0; j < 2; ++j) pB[j] += 64;
        __syncthreads();                  // drains DMA (vmcnt 0)
#pragma unroll
        for (int h = 0; h < 2; ++h) {
            const int hx = h * 32;
            short8 av[4], bv[4];
#pragma unroll
            for (int i = 0; i < 4; ++i) av[i] = *(const short8*)(As + (aoff[i] ^ hx));
#pragma unroll
            for (int i = 0; i < 4; ++i) bv[i] = *(const short8*)(As + (boff[i] ^ hx));
#pragma unroll
            for (int rt = 0; rt < 4; ++rt)
#pragma unroll
                for (int ct = 0; ct < 4; ++ct)
                    acc[rt][ct] = __builtin_amdgcn_mfma_f32_16x16x32_bf16(av[rt], bv[ct], acc[rt][ct], 0, 0, 0);
        }
    }

    // epilogue: threshold + candidate append
#pragma unroll
    for (int rt = 0; rt < 4; ++rt)
#pragma unroll
        for (int ct = 0; ct < 4; ++ct)
#pragma unroll
            for (int r = 0; r < 4; ++r) {
                float d = acc[rt][ct][r];
                if (d > THETA) {
                    int q = q0 + wq * 64 + rt * 16 + rbase + r;
                    int m = m0 + wm * 64 + ct * 16 + l16;
                    u32 pos = atomicAdd(&cnt[q], 1u);
                    if (pos < CAP) cand[(size_t)q * CAP + pos] = make_uint2((u32)m, __float_as_uint(d));
                }
            }
}

// ---------------- merge: exact top-16, softmax(-dist), weighted gather -> rb bf16 ----------------
__global__ __launch_bounds__(64, 4) void k_merge(const u32* __restrict__ cnt,
                                                 const uint2* __restrict__ cand,
                                                 const float* __restrict__ x2q,
                                                 const float* __restrict__ y2m,
                                                 const u16* __restrict__ mbf,
                                                 u16* __restrict__ rb) {
    const int q = blockIdx.x;
    const int lane = threadIdx.x;
    int n = (int)cnt[q]; if (n > CAP) n = CAP;
    const float x2 = x2q[q];
    const float dx = 1.0f - x2;
    float rv[8]; u32 mi[8];
#pragma unroll
    for (int j = 0; j < 8; ++j) {
        int idx = lane + 64 * j;
        rv[j] = 3.0e38f; mi[j] = 0;
        if (idx < n) {
            uint2 c = cand[(size_t)q * CAP + idx];
            float dot = __uint_as_float(c.y);
            float y2 = y2m[c.x];
            float sq = fmaxf(x2 + y2 - 2.0f * dot, 0.0f);
            float den = fmaxf(dx * (1.0f - y2), EPSV);
            rv[j] = sq / den;
            mi[j] = c.x;
        }
    }
    __shared__ float sdist[16];
    __shared__ u32 smi[16];
    __shared__ float swt[16];
    for (int k = 0; k < 16; ++k) {
        float lm = rv[0]; int ls = 0;
#pragma unroll
        for (int j = 1; j < 8; ++j) if (rv[j] < lm) { lm = rv[j]; ls = j; }
        unsigned long long key = (((unsigned long long)__float_as_uint(lm)) << 32) | (u32)(lane * 8 + ls);
#pragma unroll
        for (int off = 32; off; off >>= 1) {
            unsigned long long o = __shfl_xor(key, off);
            key = (o < key) ? o : key;
        }
        u32 sid = (u32)(key & 0xffffffffu);
        int wl = (int)(sid >> 3), wslot = (int)(sid & 7);
        if (lane == wl) {
            sdist[k] = rv[wslot];
            smi[k] = mi[wslot];
            rv[wslot] = 3.0e38f;
        }
    }
    __syncthreads();
    float rr = sdist[lane & 15];
    float arg = fmaxf(fmaf(2.0f, rr, 1.0f), 1.0f + EPSV);
    float dneg = -acoshf(arg);
    float mx = dneg;
#pragma unroll
    for (int off = 8; off; off >>= 1) mx = fmaxf(mx, __shfl_xor(mx, off, 16));
    float e = expf(dneg - mx);
    float ssum = e;
#pragma unroll
    for (int off = 8; off; off >>= 1) ssum += __shfl_xor(ssum, off, 16);
    if (lane < 16) swt[lane] = e / ssum;
    __syncthreads();
    float acc[4] = {0.f, 0.f, 0.f, 0.f};
    for (int k = 0; k < 16; ++k) {
        float wk = swt[k];
        const u16* mr = mbf + (size_t)smi[k] * 256;
#pragma unroll
        for (int j = 0; j < 4; ++j) acc[j] += wk * bf2f(mr[lane + 64 * j]);
    }
#pragma unroll
    for (int j = 0; j < 4; ++j) rb[(size_t)q * 256 + lane + 64 * j] = f2bf(acc[j]);
}

// ---------------- output: out = hidden + 0.1*(rb @ wp + bp) ----------------
__global__ __launch_bounds__(256) void k_out(const u16* __restrict__ rb,
                                             const u16* __restrict__ wpt,
                                             const float* __restrict__ bp,
                                             const float* __restrict__ hidden,
                                             float* __restrict__ out) {
    const int b = blockIdx.x;
    const int mt = b & 31, nt = b >> 5;
    const int t = threadIdx.x;
    const int w = t >> 6, lane = t & 63;
    const int l16 = lane & 15, kq = (lane >> 4) * 8, rbase = (lane >> 4) * 4;
    const int n = nt * 64 + w * 16 + l16;
    f32x4 zero = {0.f, 0.f, 0.f, 0.f};
    f32x4 acc[4] = {zero, zero, zero, zero};
    for (int k0 = 0; k0 < 256; k0 += 32) {
        short8 bv = *(const short8*)&wpt[(size_t)n * 256 + k0 + kq];
#pragma unroll
        for (int rt = 0; rt < 4; ++rt) {
            short8 av = *(const short8*)&rb[(size_t)(mt * 64 + rt * 16 + l16) * 256 + k0 + kq];
            acc[rt] = __builtin_amdgcn_mfma_f32_16x16x32_bf16(av, bv, acc[rt], 0, 0, 0);
        }
    }
    float bpn = bp[n];
#pragma unroll
    for (int rt = 0; rt < 4; ++rt)
#pragma unroll
        for (int r = 0; r < 4; ++r) {
            int m = mt * 64 + rt * 16 + rbase + r;
            out[(size_t)m * 1024 + n] = hidden[(size_t)m * 1024 + n] + 0.1f * (acc[rt][r] + bpn);
        }
}

extern "C" void kernel_launch(void* const* d_in, const int* in_sizes, int n_in,
                              void* d_out, int out_size, void* d_ws, size_t ws_size,
                              hipStream_t stream) {
    const float* hidden = (const float*)d_in[0];
    const float* memory = (const float*)d_in[1];
    const float* w1 = (const float*)d_in[2];
    const float* b1 = (const float*)d_in[3];
    const float* ln_g = (const float*)d_in[4];
    const float* ln_b = (const float*)d_in[5];
    const float* w2 = (const float*)d_in[6];
    const float* b2 = (const float*)d_in[7];
    const float* wp = (const float*)d_in[8];
    const float* bp = (const float*)d_in[9];
    float* out = (float*)d_out;
    char* ws = (char*)d_ws;

    u16* mbf  = (u16*)(ws);                       // 33554432
    float* y2m = (float*)(ws + 33554432);         // 262144
    u16* hb   = (u16*)(ws + 33816576);            // 4194304
    u16* w1t  = (u16*)(ws + 38010880);            // 524288
    u16* w2t  = (u16*)(ws + 38535168);            // 131072
    u16* wpt  = (u16*)(ws + 38666240);            // 524288
    u16* qg   = (u16*)(ws + 39190528);            // 1048576
    u16* qbb  = (u16*)(ws + 40239104);            // 1048576
    float* x2q = (float*)(ws + 41287680);         // 8192
    u32* cnt  = (u32*)(ws + 41295872);            // 8192
    uint2* cand = (uint2*)(ws + 41304064);        // 8388608
    u16* rb   = (u16*)(ws + 49692672);            // 1048576

    hipLaunchKernelGGL(k_pre, dim3(19968), dim3(256), 0, stream,
                       memory, mbf, y2m, cnt, hidden, hb, w1, w1t, w2, w2t, wp, wpt);
    hipLaunchKernelGGL(k_g1, dim3(128), dim3(256), 0, stream, hb, w1t, b1, ln_g, ln_b, qg);
    hipLaunchKernelGGL(k_g2, dim3(128), dim3(256), 0, stream, qg, w2t, b2, qbb, x2q);
    hipLaunchKernelGGL(k_dist, dim3(4096), dim3(512), 0, stream, qbb, mbf, cnt, cand);
    hipLaunchKernelGGL(k_merge, dim3(2048), dim3(64), 0, stream, cnt, cand, x2q, y2m, mbf, rb);
    hipLaunchKernelGGL(k_out, dim3(512), dim3(256), 0, stream, rb, wpt, bp, hidden, out);
}

// Round 7
// 303.017 us; speedup vs baseline: 1.3631x; 1.0635x over previous
//
#include <hip/hip_runtime.h>
#include <hip/hip_bf16.h>

typedef unsigned int u32;
typedef unsigned short u16;
typedef __attribute__((ext_vector_type(8))) short short8;
typedef __attribute__((ext_vector_type(4))) float f32x4;

#define EPSV 1e-5f
#define MAXN (1.0f - 1e-5f)
#define THETA 0.17f
#define CAP 512

__device__ __forceinline__ u16 f2bf(float f) {
    union { float f; u32 u; } v; v.f = f;
    u32 u = v.u;
    u32 r = (u + 0x7fffu + ((u >> 16) & 1u)) >> 16;
    return (u16)r;
}
__device__ __forceinline__ float bf2f(u16 h) {
    union { u32 u; float f; } v; v.u = ((u32)h) << 16;
    return v.f;
}

typedef __attribute__((address_space(1))) const unsigned char gbuf_t;
typedef __attribute__((address_space(3))) unsigned char lbuf_t;
__device__ __forceinline__ void gl2lds16(const void* g, void* l) {
    __builtin_amdgcn_global_load_lds((gbuf_t*)g, (lbuf_t*)l, 16, 0, 0);
}

// ---------------- fused pre: memory project + hidden->bf16 + LDS-tiled transposes ----------------
__global__ __launch_bounds__(256) void k_pre(const float* __restrict__ mem,
                                             u16* __restrict__ mbf,
                                             float* __restrict__ y2m,
                                             u32* __restrict__ cnt,
                                             const float* __restrict__ hidden, u16* __restrict__ hb,
                                             const float* __restrict__ w1, u16* __restrict__ w1t,
                                             const float* __restrict__ w2, u16* __restrict__ w2t,
                                             const float* __restrict__ wp, u16* __restrict__ wpt) {
    __shared__ float ld[64 * 65];
    const int b = blockIdx.x, t = threadIdx.x;
    if (b < 16384) {                      // memory bank: project + bf16 + y2
        int zi = b * 256 + t;
        if (zi < 2048) cnt[zi] = 0;
        const int row = b * 4 + (t >> 6);
        const int lane = t & 63;
        const float4* p = (const float4*)(mem + (size_t)row * 256);
        float4 v = p[lane];
        float ss = v.x * v.x + v.y * v.y + v.z * v.z + v.w * v.w;
#pragma unroll
        for (int off = 32; off; off >>= 1) ss += __shfl_xor(ss, off);
        float norm = sqrtf(ss);
        float scale = (norm > MAXN) ? MAXN / fmaxf(norm, EPSV) : 1.0f;
        ushort4 u;
        u.x = f2bf(v.x * scale); u.y = f2bf(v.y * scale);
        u.z = f2bf(v.z * scale); u.w = f2bf(v.w * scale);
        *(ushort4*)&mbf[(size_t)row * 256 + lane * 4] = u;
        if (lane == 0) y2m[row] = ss * scale * scale;
    } else if (b < 18432) {               // hidden f32 -> bf16
        int i = (b - 16384) * 256 + t;
        float4 v = ((const float4*)hidden)[i];
        ushort4 u; u.x = f2bf(v.x); u.y = f2bf(v.y); u.z = f2bf(v.z); u.w = f2bf(v.w);
        ((ushort4*)hb)[i] = u;
    } else {                              // transpose f32 src[K][N] -> bf16 dst[N][K], 64x64 tiles
        const float* src; u16* dst; int K, N, tile;
        int bb = b - 18432;
        if (bb < 64)      { src = w1; dst = w1t; K = 1024; N = 256;  tile = bb; }
        else if (bb < 80) { src = w2; dst = w2t; K = 256;  N = 256;  tile = bb - 64; }
        else              { src = wp; dst = wpt; K = 256;  N = 1024; tile = bb - 80; }
        int ntn = N >> 6;
        int tk = (tile / ntn) * 64, tn = (tile - (tile / ntn) * ntn) * 64;
#pragma unroll
        for (int j = 0; j < 16; ++j) {
            int lin = j * 256 + t;
            int r = lin >> 6, c = lin & 63;
            ld[r * 65 + c] = src[(size_t)(tk + r) * N + tn + c];
        }
        __syncthreads();
#pragma unroll
        for (int j = 0; j < 16; ++j) {
            int lin = j * 256 + t;
            int c2 = lin >> 6, r2 = lin & 63;
            dst[(size_t)(tn + c2) * K + tk + r2] = f2bf(ld[r2 * 65 + c2]);
        }
    }
}

// ---------------- fused query net: GEMM1 + bias + LN + GELU (LDS) + GEMM2 + bias + project ----
// grid 128, block 256 (4 waves), 16 q-rows per block.
__global__ __launch_bounds__(256) void k_qnet(const u16* __restrict__ hb,
                                              const u16* __restrict__ w1t,
                                              const float* __restrict__ b1,
                                              const float* __restrict__ lng,
                                              const float* __restrict__ lnb,
                                              const u16* __restrict__ w2t,
                                              const float* __restrict__ b2,
                                              u16* __restrict__ qbb,
                                              float* __restrict__ x2q) {
    __shared__ float sm[16 * 260];
    __shared__ u16 qs[16 * 264];
    const int t = threadIdx.x;
    const int w = t >> 6, lane = t & 63;
    const int l16 = lane & 15, kq = (lane >> 4) * 8, rbase = (lane >> 4) * 4;
    const int q0 = blockIdx.x * 16;
    f32x4 zero = {0.f, 0.f, 0.f, 0.f};

    // ---- GEMM1: 16 x 256 (K=1024)
    {
        f32x4 acc[4] = {zero, zero, zero, zero};
        const u16* ap = hb + (size_t)(q0 + l16) * 1024 + kq;
        for (int k0 = 0; k0 < 1024; k0 += 32) {
            short8 av = *(const short8*)(ap + k0);
#pragma unroll
            for (int ct = 0; ct < 4; ++ct) {
                int n = w * 64 + ct * 16 + l16;
                short8 bv = *(const short8*)&w1t[(size_t)n * 1024 + k0 + kq];
                acc[ct] = __builtin_amdgcn_mfma_f32_16x16x32_bf16(av, bv, acc[ct], 0, 0, 0);
            }
        }
#pragma unroll
        for (int ct = 0; ct < 4; ++ct) {
            int n = w * 64 + ct * 16 + l16;
            float bias = b1[n];
#pragma unroll
            for (int r = 0; r < 4; ++r)
                sm[(rbase + r) * 260 + n] = acc[ct][r] + bias;
        }
    }
    __syncthreads();
    // ---- LayerNorm + GELU -> qs (bf16 in LDS)
    {
        const int row = t >> 4, sub = t & 15;
        float s1 = 0.f, s2 = 0.f;
#pragma unroll
        for (int i = 0; i < 16; ++i) {
            float v = sm[row * 260 + sub + 16 * i];
            s1 += v; s2 += v * v;
        }
#pragma unroll
        for (int off = 8; off; off >>= 1) {
            s1 += __shfl_xor(s1, off, 16);
            s2 += __shfl_xor(s2, off, 16);
        }
        float mu = s1 * (1.0f / 256.0f);
        float var = s2 * (1.0f / 256.0f) - mu * mu;
        float rstd = rsqrtf(var + EPSV);
#pragma unroll
        for (int i = 0; i < 16; ++i) {
            int cc = sub + 16 * i;
            float v = sm[row * 260 + cc];
            float xn = (v - mu) * rstd * lng[cc] + lnb[cc];
            float ge = 0.5f * xn * (1.0f + erff(xn * 0.7071067811865475f));
            qs[row * 264 + cc] = f2bf(ge);
        }
    }
    __syncthreads();
    // ---- GEMM2: 16 x 256 (K=256), A from LDS qs
    f32x4 acc2[4] = {zero, zero, zero, zero};
    for (int k0 = 0; k0 < 256; k0 += 32) {
        short8 av = *(const short8*)&qs[l16 * 264 + k0 + kq];
#pragma unroll
        for (int ct = 0; ct < 4; ++ct) {
            int n = w * 64 + ct * 16 + l16;
            short8 bv = *(const short8*)&w2t[(size_t)n * 256 + k0 + kq];
            acc2[ct] = __builtin_amdgcn_mfma_f32_16x16x32_bf16(av, bv, acc2[ct], 0, 0, 0);
        }
    }
    __syncthreads();                      // done reading sm (GEMM1 result)
#pragma unroll
    for (int ct = 0; ct < 4; ++ct) {
        int n = w * 64 + ct * 16 + l16;
        float bias = b2[n];
#pragma unroll
        for (int r = 0; r < 4; ++r)
            sm[(rbase + r) * 260 + n] = acc2[ct][r] + bias;
    }
    __syncthreads();
    // ---- Poincare project -> qbb, x2q
    {
        const int row = t >> 4, sub = t & 15;
        float s2 = 0.f;
#pragma unroll
        for (int i = 0; i < 16; ++i) {
            float v = sm[row * 260 + sub + 16 * i];
            s2 += v * v;
        }
#pragma unroll
        for (int off = 8; off; off >>= 1) s2 += __shfl_xor(s2, off, 16);
        float norm = sqrtf(s2);
        float scale = (norm > MAXN) ? MAXN / fmaxf(norm, EPSV) : 1.0f;
        if (sub == 0) x2q[q0 + row] = s2 * scale * scale;
#pragma unroll
        for (int i = 0; i < 16; ++i) {
            int cc = sub + 16 * i;
            qbb[(size_t)(q0 + row) * 256 + cc] = f2bf(sm[row * 260 + cc] * scale);
        }
    }
}

// ---------------- main: R4 structure + phase-staggered K-loop ----------------
// 128x128 tile, BK=64, K=256 (4 stages). Stage order rotated by per-block phase
// so co-resident blocks drain their DMA at different times (accumulation over kt
// is order-independent). XCD-clustered dispatch as R4. Same XOR chunk-swizzle
// (slot = chunk ^ (r&7)) that measured 0 bank conflicts.
__global__ __launch_bounds__(256, 4) void k_dist(const u16* __restrict__ qb,
                                                 const u16* __restrict__ mbf,
                                                 u32* __restrict__ cnt,
                                                 uint2* __restrict__ cand) {
    __shared__ u16 smem[16384];           // As @0 (8192 u16), Bs @8192
    u16* As = smem;
    const int b = blockIdx.x;
    const int qt = (b >> 3) & 15;
    const int mt = ((b >> 7) << 3) | (b & 7);
    const int q0 = qt * 128, m0 = mt * 128;
    const int t = threadIdx.x;
    const int w = t >> 6, lane = t & 63;
    const int l16 = lane & 15, Q = lane >> 4, rbase = Q * 4;
    const int phase = (b >> 3) & 3;       // co-resident blocks (b, b+8, b+16, b+24) differ

    // staging: issue i = w*4+j covers rows [i*8, i*8+8), all 8 chunks (16B each)
    const u16* pA[4];
    u16* lA[4];
#pragma unroll
    for (int j = 0; j < 4; ++j) {
        int i = w * 4 + j;
        int r = i * 8 + (lane >> 3);
        int c = (lane & 7) ^ (r & 7);
        pA[j] = qb + (size_t)(q0 + r) * 256 + c * 8;
        lA[j] = As + i * 512;             // wave-uniform LDS base (64 slots * 8 u16)
    }
    const ptrdiff_t dB = (mbf + (size_t)m0 * 256) - (qb + (size_t)q0 * 256); // uniform

    // compute-side swizzled LDS offsets (u16 units); h=1 sub-step = offset ^ 32
    const int wq = w & 1, wm = w >> 1;
    int aoff[4], boff[4];
#pragma unroll
    for (int i = 0; i < 4; ++i) {
        int R = wq * 64 + i * 16 + l16;
        aoff[i] = R * 64 + ((Q ^ (R & 7)) * 8);
        int S = wm * 64 + i * 16 + l16;
        boff[i] = 8192 + S * 64 + ((Q ^ (S & 7)) * 8);
    }

    f32x4 zero = {0.f, 0.f, 0.f, 0.f};
    f32x4 acc[4][4];
#pragma unroll
    for (int i = 0; i < 4; ++i)
#pragma unroll
        for (int j = 0; j < 4; ++j) acc[i][j] = zero;

#pragma unroll 1
    for (int it = 0; it < 4; ++it) {
        const int kt = (it + phase) & 3;
        const int ko = kt * 64;
        if (it) __syncthreads();          // all waves done reading previous tile
#pragma unroll
        for (int j = 0; j < 4; ++j) {
            gl2lds16(pA[j] + ko, lA[j]);
            gl2lds16(pA[j] + dB + ko, lA[j] + 8192);
        }
        __syncthreads();                  // drains DMA (vmcnt 0)
#pragma unroll
        for (int h = 0; h < 2; ++h) {
            const int hx = h * 32;
            short8 av[4], bv[4];
#pragma unroll
            for (int i = 0; i < 4; ++i) av[i] = *(const short8*)(As + (aoff[i] ^ hx));
#pragma unroll
            for (int i = 0; i < 4; ++i) bv[i] = *(const short8*)(As + (boff[i] ^ hx));
#pragma unroll
            for (int rt = 0; rt < 4; ++rt)
#pragma unroll
                for (int ct = 0; ct < 4; ++ct)
                    acc[rt][ct] = __builtin_amdgcn_mfma_f32_16x16x32_bf16(av[rt], bv[ct], acc[rt][ct], 0, 0, 0);
        }
    }

    // epilogue: threshold + candidate append
#pragma unroll
    for (int rt = 0; rt < 4; ++rt)
#pragma unroll
        for (int ct = 0; ct < 4; ++ct)
#pragma unroll
            for (int r = 0; r < 4; ++r) {
                float d = acc[rt][ct][r];
                if (d > THETA) {
                    int q = q0 + wq * 64 + rt * 16 + rbase + r;
                    int m = m0 + wm * 64 + ct * 16 + l16;
                    u32 pos = atomicAdd(&cnt[q], 1u);
                    if (pos < CAP) cand[(size_t)q * CAP + pos] = make_uint2((u32)m, __float_as_uint(d));
                }
            }
}

// ---------------- merge: exact top-16, softmax(-dist), weighted gather -> rb bf16 ----------------
__global__ __launch_bounds__(64, 4) void k_merge(const u32* __restrict__ cnt,
                                                 const uint2* __restrict__ cand,
                                                 const float* __restrict__ x2q,
                                                 const float* __restrict__ y2m,
                                                 const u16* __restrict__ mbf,
                                                 u16* __restrict__ rb) {
    const int q = blockIdx.x;
    const int lane = threadIdx.x;
    int n = (int)cnt[q]; if (n > CAP) n = CAP;
    const float x2 = x2q[q];
    const float dx = 1.0f - x2;
    float rv[8]; u32 mi[8];
#pragma unroll
    for (int j = 0; j < 8; ++j) {
        int idx = lane + 64 * j;
        rv[j] = 3.0e38f; mi[j] = 0;
        if (idx < n) {
            uint2 c = cand[(size_t)q * CAP + idx];
            float dot = __uint_as_float(c.y);
            float y2 = y2m[c.x];
            float sq = fmaxf(x2 + y2 - 2.0f * dot, 0.0f);
            float den = fmaxf(dx * (1.0f - y2), EPSV);
            rv[j] = sq / den;
            mi[j] = c.x;
        }
    }
    __shared__ float sdist[16];
    __shared__ u32 smi[16];
    __shared__ float swt[16];
    for (int k = 0; k < 16; ++k) {
        float lm = rv[0]; int ls = 0;
#pragma unroll
        for (int j = 1; j < 8; ++j) if (rv[j] < lm) { lm = rv[j]; ls = j; }
        unsigned long long key = (((unsigned long long)__float_as_uint(lm)) << 32) | (u32)(lane * 8 + ls);
#pragma unroll
        for (int off = 32; off; off >>= 1) {
            unsigned long long o = __shfl_xor(key, off);
            key = (o < key) ? o : key;
        }
        u32 sid = (u32)(key & 0xffffffffu);
        int wl = (int)(sid >> 3), wslot = (int)(sid & 7);
        if (lane == wl) {
            sdist[k] = rv[wslot];
            smi[k] = mi[wslot];
            rv[wslot] = 3.0e38f;
        }
    }
    __syncthreads();
    float rr = sdist[lane & 15];
    float arg = fmaxf(fmaf(2.0f, rr, 1.0f), 1.0f + EPSV);
    float dneg = -acoshf(arg);
    float mx = dneg;
#pragma unroll
    for (int off = 8; off; off >>= 1) mx = fmaxf(mx, __shfl_xor(mx, off, 16));
    float e = expf(dneg - mx);
    float ssum = e;
#pragma unroll
    for (int off = 8; off; off >>= 1) ssum += __shfl_xor(ssum, off, 16);
    if (lane < 16) swt[lane] = e / ssum;
    __syncthreads();
    float acc[4] = {0.f, 0.f, 0.f, 0.f};
    for (int k = 0; k < 16; ++k) {
        float wk = swt[k];
        const u16* mr = mbf + (size_t)smi[k] * 256;
#pragma unroll
        for (int j = 0; j < 4; ++j) acc[j] += wk * bf2f(mr[lane + 64 * j]);
    }
#pragma unroll
    for (int j = 0; j < 4; ++j) rb[(size_t)q * 256 + lane + 64 * j] = f2bf(acc[j]);
}

// ---------------- output: out = hidden + 0.1*(rb @ wp + bp) ----------------
__global__ __launch_bounds__(256) void k_out(const u16* __restrict__ rb,
                                             const u16* __restrict__ wpt,
                                             const float* __restrict__ bp,
                                             const float* __restrict__ hidden,
                                             float* __restrict__ out) {
    const int b = blockIdx.x;
    const int mt = b & 31, nt = b >> 5;
    const int t = threadIdx.x;
    const int w = t >> 6, lane = t & 63;
    const int l16 = lane & 15, kq = (lane >> 4) * 8, rbase = (lane >> 4) * 4;
    const int n = nt * 64 + w * 16 + l16;
    f32x4 zero = {0.f, 0.f, 0.f, 0.f};
    f32x4 acc[4] = {zero, zero, zero, zero};
    for (int k0 = 0; k0 < 256; k0 += 32) {
        short8 bv = *(const short8*)&wpt[(size_t)n * 256 + k0 + kq];
#pragma unroll
        for (int rt = 0; rt < 4; ++rt) {
            short8 av = *(const short8*)&rb[(size_t)(mt * 64 + rt * 16 + l16) * 256 + k0 + kq];
            acc[rt] = __builtin_amdgcn_mfma_f32_16x16x32_bf16(av, bv, acc[rt], 0, 0, 0);
        }
    }
    float bpn = bp[n];
#pragma unroll
    for (int rt = 0; rt < 4; ++rt)
#pragma unroll
        for (int r = 0; r < 4; ++r) {
            int m = mt * 64 + rt * 16 + rbase + r;
            out[(size_t)m * 1024 + n] = hidden[(size_t)m * 1024 + n] + 0.1f * (acc[rt][r] + bpn);
        }
}

extern "C" void kernel_launch(void* const* d_in, const int* in_sizes, int n_in,
                              void* d_out, int out_size, void* d_ws, size_t ws_size,
                              hipStream_t stream) {
    const float* hidden = (const float*)d_in[0];
    const float* memory = (const float*)d_in[1];
    const float* w1 = (const float*)d_in[2];
    const float* b1 = (const float*)d_in[3];
    const float* ln_g = (const float*)d_in[4];
    const float* ln_b = (const float*)d_in[5];
    const float* w2 = (const float*)d_in[6];
    const float* b2 = (const float*)d_in[7];
    const float* wp = (const float*)d_in[8];
    const float* bp = (const float*)d_in[9];
    float* out = (float*)d_out;
    char* ws = (char*)d_ws;

    u16* mbf  = (u16*)(ws);                       // 33554432
    float* y2m = (float*)(ws + 33554432);         // 262144
    u16* hb   = (u16*)(ws + 33816576);            // 4194304
    u16* w1t  = (u16*)(ws + 38010880);            // 524288
    u16* w2t  = (u16*)(ws + 38535168);            // 131072
    u16* wpt  = (u16*)(ws + 38666240);            // 524288
    u16* qbb  = (u16*)(ws + 40239104);            // 1048576
    float* x2q = (float*)(ws + 41287680);         // 8192
    u32* cnt  = (u32*)(ws + 41295872);            // 8192
    uint2* cand = (uint2*)(ws + 41304064);        // 8388608
    u16* rb   = (u16*)(ws + 49692672);            // 1048576

    hipLaunchKernelGGL(k_pre, dim3(18576), dim3(256), 0, stream,
                       memory, mbf, y2m, cnt, hidden, hb, w1, w1t, w2, w2t, wp, wpt);
    hipLaunchKernelGGL(k_qnet, dim3(128), dim3(256), 0, stream,
                       hb, w1t, b1, ln_g, ln_b, w2t, b2, qbb, x2q);
    hipLaunchKernelGGL(k_dist, dim3(8192), dim3(256), 0, stream, qbb, mbf, cnt, cand);
    hipLaunchKernelGGL(k_merge, dim3(2048), dim3(64), 0, stream, cnt, cand, x2q, y2m, mbf, rb);
    hipLaunchKernelGGL(k_out, dim3(512), dim3(256), 0, stream, rb, wpt, bp, hidden, out);
}